// Round 6
// baseline (26.872 us; speedup 1.0000x reference)
//
#include <hip/hip_runtime.h>
#include <hip/hip_bf16.h>

#define DIM   768
#define KITER (DIM / 32)          // 24 MFMA k-steps
#define EPSF  1e-6f
#define MAXB  4096
#define NPB   256                 // pairs blocks (4 waves each)

typedef __attribute__((ext_vector_type(4))) float f32x4;
typedef __attribute__((ext_vector_type(8))) short short8;
typedef __attribute__((ext_vector_type(4))) unsigned short ushort4_t;

// ---------------- ws layout ----------------
// [0)        int   cnt[2]            (written by k_norms last-row wave)
// [64)       float d2A[4096]         ||e+eps||^2, compacted A order
// [64+16K)   float s2B[4096]         ||e||^2,     compacted B order
// [64+32K)   float partials[NPB]     (4K reserved)
// [36928)    int   idxA[4096]        (fallback path only)
// [53312)    int   idxB[4096]
// [69696)    COMP: ushort Abf[4096*768], ushort Bbf[4096*768]   (12.6 MB)
#define OFF_D2A   64
#define OFF_S2B   (64 + 16384)
#define OFF_PART  (64 + 32768)
#define OFF_IDXA  (64 + 32768 + 4096)
#define OFF_IDXB  (OFF_IDXA + 16384)
#define OFF_BF    (OFF_IDXB + 16384)
#define NEED_COMP ((size_t)OFF_BF + 2ull * MAXB * DIM * 2ull)

__device__ __forceinline__ unsigned short f2bf(float f) {
    return __builtin_bit_cast(unsigned short, __float2bfloat16(f));
}

__device__ __forceinline__ float hinge_from_d2(float dist2) {
    float dist = sqrtf(fmaxf(dist2, 1e-12f));
    return fmaxf(1.0f - dist, 0.0f);
}

template <bool ADD_EPS>
__device__ __forceinline__ short8 load_frag(const float* __restrict__ p) {
    const float4 u = *reinterpret_cast<const float4*>(p);
    const float4 v = *reinterpret_cast<const float4*>(p + 4);
    short8 f;
    if constexpr (ADD_EPS) {
        f[0] = (short)f2bf(u.x + EPSF); f[1] = (short)f2bf(u.y + EPSF);
        f[2] = (short)f2bf(u.z + EPSF); f[3] = (short)f2bf(u.w + EPSF);
        f[4] = (short)f2bf(v.x + EPSF); f[5] = (short)f2bf(v.y + EPSF);
        f[6] = (short)f2bf(v.z + EPSF); f[7] = (short)f2bf(v.w + EPSF);
    } else {
        f[0] = (short)f2bf(u.x); f[1] = (short)f2bf(u.y);
        f[2] = (short)f2bf(u.z); f[3] = (short)f2bf(u.w);
        f[4] = (short)f2bf(v.x); f[5] = (short)f2bf(v.y);
        f[6] = (short)f2bf(v.z); f[7] = (short)f2bf(v.w);
    }
    return f;
}

// One wave per ORIGINAL row. Member waves compute their compacted slot by a
// redundant lane-strided prefix count over labels[0..row) -- no inter-block
// communication, no atomics, no separate classify dispatch. The wave owning
// the last row also writes cnt[0..1]. COMP: writes the bf16 row (A side with
// +eps baked in) to the compacted buffer; always writes fp32 norms + idx.
template <bool COMP>
__global__ void k_norms(const float* __restrict__ emb,
                        const int* __restrict__ labels,
                        const int* __restrict__ depi,
                        const int* __restrict__ suii,
                        int* __restrict__ cnt,
                        int* __restrict__ idxA, int* __restrict__ idxB,
                        float* __restrict__ d2A, float* __restrict__ s2B,
                        unsigned short* __restrict__ Abf,
                        unsigned short* __restrict__ Bbf, int nrows)
{
    const int row  = blockIdx.x * 4 + (threadIdx.x >> 6);
    const int lane = threadIdx.x & 63;
    if (row >= nrows) return;
    const int dep = depi[0], sui = suii[0];
    const int lab = labels[row];
    const bool isA = (lab == dep), isB = (lab == sui);
    const bool isLast = (row == nrows - 1);
    if (!(isA | isB) && !isLast) return;          // wave-uniform early exit

    // prefix counts over labels[0..row): packed (A | B<<16), <=4096 each
    int packed = 0;
    for (int j = lane; j < row; j += 64) {
        const int l = labels[j];
        packed += (l == dep) + ((l == sui) << 16);
    }
    #pragma unroll
    for (int off = 32; off; off >>= 1) packed += __shfl_xor(packed, off);
    const int pA = packed & 0xFFFF;
    const int pB = packed >> 16;
    if (isLast && lane == 0) {
        cnt[0] = pA + (isA ? 1 : 0);
        cnt[1] = pB + (isB ? 1 : 0);
    }
    if (!(isA | isB)) return;

    const float* rp = emb + (size_t)row * DIM;
    float4 v[3];
    float s2 = 0.f, d2 = 0.f;
    #pragma unroll
    for (int c = 0; c < 3; ++c) {
        v[c] = *reinterpret_cast<const float4*>(rp + c * 256 + lane * 4);
        s2 += v[c].x * v[c].x + v[c].y * v[c].y + v[c].z * v[c].z + v[c].w * v[c].w;
        const float dx = v[c].x + EPSF, dy = v[c].y + EPSF;
        const float dz = v[c].z + EPSF, dw = v[c].w + EPSF;
        d2 += dx * dx + dy * dy + dz * dz + dw * dw;
    }
    int pk2 = __builtin_bit_cast(int, s2);
    float d2r = d2;
    #pragma unroll
    for (int off = 32; off; off >>= 1) {
        pk2 = __builtin_bit_cast(int,
              __builtin_bit_cast(float, pk2) + __shfl_xor(__builtin_bit_cast(float, pk2), off));
        d2r += __shfl_xor(d2r, off);
    }
    const float s2t = __builtin_bit_cast(float, pk2);

    if (isA) {
        if (lane == 0) { d2A[pA] = d2r; idxA[pA] = row; }
        if constexpr (COMP) {
            unsigned short* dst = Abf + (size_t)pA * DIM;
            #pragma unroll
            for (int c = 0; c < 3; ++c) {
                ushort4_t wd;
                wd[0] = f2bf(v[c].x + EPSF); wd[1] = f2bf(v[c].y + EPSF);
                wd[2] = f2bf(v[c].z + EPSF); wd[3] = f2bf(v[c].w + EPSF);
                *reinterpret_cast<ushort4_t*>(dst + c * 256 + lane * 4) = wd;
            }
        }
    }
    if (isB) {
        if (lane == 0) { s2B[pB] = s2t; idxB[pB] = row; }
        if constexpr (COMP) {
            unsigned short* dst = Bbf + (size_t)pB * DIM;
            #pragma unroll
            for (int c = 0; c < 3; ++c) {
                ushort4_t wd;
                wd[0] = f2bf(v[c].x); wd[1] = f2bf(v[c].y);
                wd[2] = f2bf(v[c].z); wd[3] = f2bf(v[c].w);
                *reinterpret_cast<ushort4_t*>(dst + c * 256 + lane * 4) = wd;
            }
        }
    }
}

// Each wave owns a 32x32 pair tile = 2x2 MFMA(16x16x32) sub-tiles -> 4
// independent accumulator chains. t = bid + wv*grid spreads the ~484 active
// waves across distinct blocks/CUs. One plain partial store per block.
template <bool COMP>
__global__ void __launch_bounds__(256)
k_pairs(const float* __restrict__ emb,
        const int* __restrict__ cnt,
        const float* __restrict__ d2A, const float* __restrict__ s2B,
        const int* __restrict__ idxA, const int* __restrict__ idxB,
        const unsigned short* __restrict__ Abf,
        const unsigned short* __restrict__ Bbf,
        float* __restrict__ partials)
{
    __shared__ float wsum[4];
    const int nA = cnt[0], nB = cnt[1];
    const unsigned nTi = (unsigned)(nA + 31) >> 5;
    const unsigned nTj = (unsigned)(nB + 31) >> 5;
    const unsigned T   = nTi * nTj;
    const int tid = threadIdx.x, wv = tid >> 6, lane = tid & 63;
    const int r = lane & 15, kq = lane >> 4;
    float wacc = 0.f;

    for (unsigned t = blockIdx.x + wv * gridDim.x; t < T; t += gridDim.x * 4) {
        const unsigned ti = t / nTj;
        const unsigned tj = t - ti * nTj;
        const int a0 = (int)(ti << 5), b0 = (int)(tj << 5);
        const int ar0 = min(a0 + r,      nA - 1);   // clamp; epilogue masks
        const int ar1 = min(a0 + 16 + r, nA - 1);
        const int br0 = min(b0 + r,      nB - 1);
        const int br1 = min(b0 + 16 + r, nB - 1);
        f32x4 acc00 = {0.f,0.f,0.f,0.f}, acc01 = {0.f,0.f,0.f,0.f};
        f32x4 acc10 = {0.f,0.f,0.f,0.f}, acc11 = {0.f,0.f,0.f,0.f};

        if constexpr (COMP) {
            const short8* pa0 = reinterpret_cast<const short8*>(Abf + (size_t)ar0 * DIM) + kq;
            const short8* pa1 = reinterpret_cast<const short8*>(Abf + (size_t)ar1 * DIM) + kq;
            const short8* pb0 = reinterpret_cast<const short8*>(Bbf + (size_t)br0 * DIM) + kq;
            const short8* pb1 = reinterpret_cast<const short8*>(Bbf + (size_t)br1 * DIM) + kq;
            #pragma unroll 6
            for (int kk = 0; kk < KITER; ++kk) {
                const short8 fa0 = pa0[4 * kk], fa1 = pa1[4 * kk];
                const short8 fb0 = pb0[4 * kk], fb1 = pb1[4 * kk];
                acc00 = __builtin_amdgcn_mfma_f32_16x16x32_bf16(fa0, fb0, acc00, 0, 0, 0);
                acc01 = __builtin_amdgcn_mfma_f32_16x16x32_bf16(fa0, fb1, acc01, 0, 0, 0);
                acc10 = __builtin_amdgcn_mfma_f32_16x16x32_bf16(fa1, fb0, acc10, 0, 0, 0);
                acc11 = __builtin_amdgcn_mfma_f32_16x16x32_bf16(fa1, fb1, acc11, 0, 0, 0);
            }
        } else {
            const float* qa0 = emb + (size_t)idxA[ar0] * DIM + kq * 8;
            const float* qa1 = emb + (size_t)idxA[ar1] * DIM + kq * 8;
            const float* qb0 = emb + (size_t)idxB[br0] * DIM + kq * 8;
            const float* qb1 = emb + (size_t)idxB[br1] * DIM + kq * 8;
            #pragma unroll 3
            for (int kk = 0; kk < KITER; ++kk) {
                const short8 fa0 = load_frag<true >(qa0 + 32 * kk);
                const short8 fa1 = load_frag<true >(qa1 + 32 * kk);
                const short8 fb0 = load_frag<false>(qb0 + 32 * kk);
                const short8 fb1 = load_frag<false>(qb1 + 32 * kk);
                acc00 = __builtin_amdgcn_mfma_f32_16x16x32_bf16(fa0, fb0, acc00, 0, 0, 0);
                acc01 = __builtin_amdgcn_mfma_f32_16x16x32_bf16(fa0, fb1, acc01, 0, 0, 0);
                acc10 = __builtin_amdgcn_mfma_f32_16x16x32_bf16(fa1, fb0, acc10, 0, 0, 0);
                acc11 = __builtin_amdgcn_mfma_f32_16x16x32_bf16(fa1, fb1, acc11, 0, 0, 0);
            }
        }

        // C/D mapping: col = lane&15 (B idx), row = (lane>>4)*4 + reg (A idx)
        const int bc0 = b0 + r, bc1 = b0 + 16 + r;
        const float s20 = (bc0 < nB) ? s2B[bc0] : 0.f;
        const float s21 = (bc1 < nB) ? s2B[bc1] : 0.f;
        #pragma unroll
        for (int j = 0; j < 4; ++j) {
            const int arl = a0 + (kq << 2) + j;
            const int arh = arl + 16;
            const float d2l = (arl < nA) ? d2A[arl] : 0.f;
            const float d2h = (arh < nA) ? d2A[arh] : 0.f;
            if (arl < nA && bc0 < nB) wacc += hinge_from_d2(d2l + s20 - 2.f * acc00[j]);
            if (arl < nA && bc1 < nB) wacc += hinge_from_d2(d2l + s21 - 2.f * acc01[j]);
            if (arh < nA && bc0 < nB) wacc += hinge_from_d2(d2h + s20 - 2.f * acc10[j]);
            if (arh < nA && bc1 < nB) wacc += hinge_from_d2(d2h + s21 - 2.f * acc11[j]);
        }
    }

    #pragma unroll
    for (int off = 32; off; off >>= 1) wacc += __shfl_down(wacc, off);
    if (lane == 0) wsum[wv] = wacc;
    __syncthreads();
    if (tid == 0)
        partials[blockIdx.x] = wsum[0] + wsum[1] + wsum[2] + wsum[3];
}

// Tiny deterministic tree reduce of NPB partials + final divide.
__global__ void __launch_bounds__(NPB)
k_final(const float* __restrict__ partials, const int* __restrict__ cnt,
        float* __restrict__ out)
{
    __shared__ float sm[NPB];
    const int tid = threadIdx.x;
    sm[tid] = partials[tid];
    __syncthreads();
    for (int off = NPB / 2; off; off >>= 1) {
        if (tid < off) sm[tid] += sm[tid + off];
        __syncthreads();
    }
    if (tid == 0) {
        const long long c = (long long)cnt[0] * (long long)cnt[1];
        out[0] = (c > 0) ? sm[0] / (float)c : 0.f;
    }
}

extern "C" void kernel_launch(void* const* d_in, const int* in_sizes, int n_in,
                              void* d_out, int out_size, void* d_ws, size_t ws_size,
                              hipStream_t stream)
{
    const float* emb  = (const float*)d_in[0];
    const int* labels = (const int*)d_in[1];
    const int* depi   = (const int*)d_in[2];
    const int* suii   = (const int*)d_in[3];
    float* out        = (float*)d_out;

    char* ws = (char*)d_ws;
    int*   cnt      = (int*)ws;
    float* d2A      = (float*)(ws + OFF_D2A);
    float* s2B      = (float*)(ws + OFF_S2B);
    float* partials = (float*)(ws + OFF_PART);
    int*   idxA     = (int*)(ws + OFF_IDXA);
    int*   idxB     = (int*)(ws + OFF_IDXB);
    unsigned short* Abf = (unsigned short*)(ws + OFF_BF);
    unsigned short* Bbf = Abf + (size_t)MAXB * DIM;

    const int nrows = in_sizes[0] / DIM;           // 4096
    const int nblk  = (nrows + 3) / 4;             // one wave per row

    if (ws_size >= NEED_COMP) {
        k_norms<true><<<nblk, 256, 0, stream>>>(emb, labels, depi, suii, cnt,
                                                idxA, idxB, d2A, s2B, Abf, Bbf, nrows);
        k_pairs<true><<<NPB, 256, 0, stream>>>(emb, cnt, d2A, s2B, idxA, idxB,
                                               Abf, Bbf, partials);
    } else {
        k_norms<false><<<nblk, 256, 0, stream>>>(emb, labels, depi, suii, cnt,
                                                 idxA, idxB, d2A, s2B, Abf, Bbf, nrows);
        k_pairs<false><<<NPB, 256, 0, stream>>>(emb, cnt, d2A, s2B, idxA, idxB,
                                                Abf, Bbf, partials);
    }
    k_final<<<1, NPB, 0, stream>>>(partials, cnt, out);
}